// Round 5
// baseline (226.788 us; speedup 1.0000x reference)
//
#include <hip/hip_runtime.h>

// YOLO loss: predictions (N,7,7,30) f32, target (N,7,7,25) f32 -> scalar f32.
// S=7, B=2, C=20. Memory-bound reduction (~176 MB -> 1 float).
//
// Round 5:
//  - CPB=128 cells/block, TPB=256 (4 waves): LDS 28160 B -> 5 blocks/CU
//    (20 waves/CU cap) and only 6272 workgroups (halves dispatch pressure
//    vs round 4's 12544 short-lived blocks).
//  - global_load_lds width=16 staging, ~7 ops/wave, evenly spread.
//  - wave role-split: waves 0,1 = geometry (iou/coord/conf), waves 2,3 =
//    class SSE, each on its 64-cell half.
//  - fused finalization: last-block-done atomic counter, fixed-order sum
//    (deterministic), no second kernel launch.

#define S7 7
#define CELL_P 30
#define CELL_T 25
#define TPB 256
#define CPB 128

__device__ __forceinline__ void gload16(const void* g, void* l)
{
    __builtin_amdgcn_global_load_lds(
        (const __attribute__((address_space(1))) unsigned int*)g,
        (__attribute__((address_space(3))) unsigned int*)l, 16, 0, 0);
}

__global__ __launch_bounds__(TPB) void yolo_fused_kernel(
    const float* __restrict__ pred, const float* __restrict__ tgt,
    float* __restrict__ partial, unsigned int* __restrict__ cnt,
    float* __restrict__ out, float invN, int nblocks)
{
    __shared__ float sp[CPB * CELL_P];   // 15360 B, linear global layout
    __shared__ float st[CPB * CELL_T];   // 12800 B
    __shared__ float sred[4];
    __shared__ bool  sdone;

    const int t    = threadIdx.x;
    const int lane = t & 63;
    const int wid  = t >> 6;
    const int bid  = blockIdx.x;

    const char* P = (const char*)(pred + (size_t)bid * CPB * CELL_P); // 15360 B
    const char* T = (const char*)(tgt  + (size_t)bid * CPB * CELL_T); // 12800 B

    // ---- stage via global_load_lds (1 KB per op: 64 lanes x 16 B) ----
    // pred: 15 chunks of 1024 B; tgt: 12 chunks + 512 B tail.
    if (wid == 0 && lane < 32)
        gload16(T + 12288 + lane * 16, (char*)st + 12288);
    #pragma unroll
    for (int i = 0; i < 4; ++i) {
        int c = wid + 4 * i;
        if (c < 15) gload16(P + c * 1024 + lane * 16, (char*)sp + c * 1024);
    }
    #pragma unroll
    for (int i = 0; i < 3; ++i) {
        int c = wid + 4 * i;
        gload16(T + c * 1024 + lane * 16, (char*)st + c * 1024);
    }
    __syncthreads();   // drains vmcnt before barrier

    float acc = 0.0f;
    const int cib = (wid & 1) * 64 + lane;          // cell within block, 0..127
    const float* pv = sp + cib * CELL_P;
    const float* tv = st + cib * CELL_T;

    if (wid < 2) {
        // ---- geometry waves: iou/argmax/coord/conf ----
        int cell = bid * CPB + cib;
        int rem  = cell % 49;
        float gx = (float)(rem % S7);   // column (axis 2)
        float gy = (float)(rem / S7);   // row    (axis 1)

        float obj = (tv[4] > 0.5f) ? 1.0f : 0.0f;

        float gcx = (gx + tv[0]) * 64.0f;
        float gcy = (gy + tv[1]) * 64.0f;
        float gw  = tv[2] * 448.0f;
        float gh  = tv[3] * 448.0f;
        float gx1 = gcx - gw * 0.5f, gy1 = gcy - gh * 0.5f;
        float gx2 = gcx + gw * 0.5f, gy2 = gcy + gh * 0.5f;
        float ga  = gw * gh;

        float iou[2], dxy[2], dwh[2], conf[2];
        #pragma unroll
        for (int b = 0; b < 2; ++b) {
            float b0 = pv[b * 5 + 0], b1 = pv[b * 5 + 1], b2 = pv[b * 5 + 2];
            float b3 = pv[b * 5 + 3], b4 = pv[b * 5 + 4];
            float pcx = (gx + b0) * 64.0f;
            float pcy = (gy + b1) * 64.0f;
            float pw  = b2 * 448.0f;
            float ph  = b3 * 448.0f;
            float px1 = pcx - pw * 0.5f, py1 = pcy - ph * 0.5f;
            float px2 = pcx + pw * 0.5f, py2 = pcy + ph * 0.5f;
            float pa  = pw * ph;

            float iw = fmaxf(fminf(px2, gx2) - fmaxf(px1, gx1), 0.0f);
            float ih = fmaxf(fminf(py2, gy2) - fmaxf(py1, gy1), 0.0f);
            float inter = iw * ih;
            iou[b] = inter / (pa + ga - inter + 1e-6f);

            float dx = b0 - tv[0], dy = b1 - tv[1];
            dxy[b] = dx * dx + dy * dy;
            float sw = sqrtf(fmaxf(b2, 0.0f)) - sqrtf(fmaxf(tv[2], 0.0f));
            float sh = sqrtf(fmaxf(b3, 0.0f)) - sqrtf(fmaxf(tv[3], 0.0f));
            dwh[b] = sw * sw + sh * sh;
            conf[b] = b4;
        }

        int best = (iou[1] > iou[0]) ? 1 : 0;   // argmax ties -> first (box 0)

        #pragma unroll
        for (int b = 0; b < 2; ++b) {
            float resp_obj = (b == best) ? obj : 0.0f;
            acc += 5.0f * resp_obj * (dxy[b] + dwh[b]);          // coord
            float d = conf[b] - iou[b];
            acc += resp_obj * d * d;                              // conf obj
            acc += 0.5f * (1.0f - resp_obj) * conf[b] * conf[b];  // conf noobj
        }
    } else {
        // ---- class waves: obj * sum((pred_cls - gt_cls)^2) ----
        float obj = (tv[4] > 0.5f) ? 1.0f : 0.0f;
        float cls = 0.0f;
        #pragma unroll
        for (int c = 0; c < 20; ++c) {
            float d = pv[10 + c] - tv[5 + c];
            cls += d * d;
        }
        acc = obj * cls;
    }

    // ---- per-wave reduce, then block sum ----
    #pragma unroll
    for (int off = 32; off > 0; off >>= 1)
        acc += __shfl_down(acc, off, 64);
    if (lane == 0) sred[wid] = acc;
    __syncthreads();
    if (t == 0) {
        partial[bid] = sred[0] + sred[1] + sred[2] + sred[3];
        __threadfence();
        unsigned int old = atomicAdd(cnt, 1u);
        sdone = (old == (unsigned int)(nblocks - 1));
    }
    __syncthreads();

    // ---- last block: deterministic fixed-order final sum ----
    if (sdone) {
        __threadfence();
        float s = 0.0f;
        for (int i = t; i < nblocks; i += TPB)
            s += partial[i];
        #pragma unroll
        for (int off = 32; off > 0; off >>= 1)
            s += __shfl_down(s, off, 64);
        __syncthreads();
        if (lane == 0) sred[wid] = s;
        __syncthreads();
        if (t == 0)
            out[0] = (sred[0] + sred[1] + sred[2] + sred[3]) * invN;
    }
}

extern "C" void kernel_launch(void* const* d_in, const int* in_sizes, int n_in,
                              void* d_out, int out_size, void* d_ws, size_t ws_size,
                              hipStream_t stream)
{
    const float* pred = (const float*)d_in[0];
    const float* tgt  = (const float*)d_in[1];
    float* out        = (float*)d_out;
    float* partial    = (float*)d_ws;

    int ncells  = in_sizes[0] / CELL_P;   // N*S*S = 802816
    int N       = ncells / 49;
    int nblocks = ncells / CPB;           // 6272, no tail
    unsigned int* cnt = (unsigned int*)((char*)d_ws + (size_t)nblocks * sizeof(float));

    hipMemsetAsync(cnt, 0, sizeof(unsigned int), stream);
    yolo_fused_kernel<<<nblocks, TPB, 0, stream>>>(pred, tgt, partial, cnt, out,
                                                   1.0f / (float)N, nblocks);
}

// Round 6
// 33.359 us; speedup vs baseline: 6.7985x; 6.7985x over previous
//
#include <hip/hip_runtime.h>

// YOLO loss: predictions (N,7,7,30) f32, target (N,7,7,25) f32 -> scalar f32.
// S=7, B=2, C=20. Memory-bound reduction (~176 MB -> 1 float).
//
// Round 6: round-4 two-kernel structure (no per-block __threadfence -- the
// agent-scope release emits buffer_wbl2, 6272 L2 flushes killed round 5),
// with round-5's tile shape (CPB=128, TPB=256: 6272 blocks, 52% occupancy).
//  - global_load_lds width=16 staging, ~7 ops/wave, linear LDS.
//  - wave role-split: waves 0,1 = geometry terms, waves 2,3 = class SSE.
//  - final kernel: 1 block, float4 reads of the 6272 partials.

#define S7 7
#define CELL_P 30
#define CELL_T 25
#define TPB 256
#define CPB 128

__device__ __forceinline__ void gload16(const void* g, void* l)
{
    __builtin_amdgcn_global_load_lds(
        (const __attribute__((address_space(1))) unsigned int*)g,
        (__attribute__((address_space(3))) unsigned int*)l, 16, 0, 0);
}

__global__ __launch_bounds__(TPB) void yolo_cell_kernel(
    const float* __restrict__ pred, const float* __restrict__ tgt,
    float* __restrict__ partial)
{
    __shared__ float sp[CPB * CELL_P];   // 15360 B, linear global layout
    __shared__ float st[CPB * CELL_T];   // 12800 B
    __shared__ float sred[4];

    const int t    = threadIdx.x;
    const int lane = t & 63;
    const int wid  = t >> 6;
    const int bid  = blockIdx.x;

    const char* P = (const char*)(pred + (size_t)bid * CPB * CELL_P); // 15360 B
    const char* T = (const char*)(tgt  + (size_t)bid * CPB * CELL_T); // 12800 B

    // ---- stage via global_load_lds (1 KB per op: 64 lanes x 16 B) ----
    // pred: 15 x 1KB chunks; tgt: 12 x 1KB chunks + 512 B tail.
    if (wid == 0 && lane < 32)
        gload16(T + 12288 + lane * 16, (char*)st + 12288);
    #pragma unroll
    for (int i = 0; i < 4; ++i) {
        int c = wid + 4 * i;
        if (c < 15) gload16(P + c * 1024 + lane * 16, (char*)sp + c * 1024);
    }
    #pragma unroll
    for (int i = 0; i < 3; ++i) {
        int c = wid + 4 * i;
        gload16(T + c * 1024 + lane * 16, (char*)st + c * 1024);
    }
    __syncthreads();   // drains vmcnt before barrier

    float acc = 0.0f;
    const int cib = (wid & 1) * 64 + lane;          // cell within block, 0..127
    const float* pv = sp + cib * CELL_P;
    const float* tv = st + cib * CELL_T;

    if (wid < 2) {
        // ---- geometry waves: iou/argmax/coord/conf ----
        int cell = bid * CPB + cib;
        int rem  = cell % 49;
        float gx = (float)(rem % S7);   // column (axis 2)
        float gy = (float)(rem / S7);   // row    (axis 1)

        float obj = (tv[4] > 0.5f) ? 1.0f : 0.0f;

        float gcx = (gx + tv[0]) * 64.0f;
        float gcy = (gy + tv[1]) * 64.0f;
        float gw  = tv[2] * 448.0f;
        float gh  = tv[3] * 448.0f;
        float gx1 = gcx - gw * 0.5f, gy1 = gcy - gh * 0.5f;
        float gx2 = gcx + gw * 0.5f, gy2 = gcy + gh * 0.5f;
        float ga  = gw * gh;

        float iou[2], dxy[2], dwh[2], conf[2];
        #pragma unroll
        for (int b = 0; b < 2; ++b) {
            float b0 = pv[b * 5 + 0], b1 = pv[b * 5 + 1], b2 = pv[b * 5 + 2];
            float b3 = pv[b * 5 + 3], b4 = pv[b * 5 + 4];
            float pcx = (gx + b0) * 64.0f;
            float pcy = (gy + b1) * 64.0f;
            float pw  = b2 * 448.0f;
            float ph  = b3 * 448.0f;
            float px1 = pcx - pw * 0.5f, py1 = pcy - ph * 0.5f;
            float px2 = pcx + pw * 0.5f, py2 = pcy + ph * 0.5f;
            float pa  = pw * ph;

            float iw = fmaxf(fminf(px2, gx2) - fmaxf(px1, gx1), 0.0f);
            float ih = fmaxf(fminf(py2, gy2) - fmaxf(py1, gy1), 0.0f);
            float inter = iw * ih;
            iou[b] = inter / (pa + ga - inter + 1e-6f);

            float dx = b0 - tv[0], dy = b1 - tv[1];
            dxy[b] = dx * dx + dy * dy;
            float sw = sqrtf(fmaxf(b2, 0.0f)) - sqrtf(fmaxf(tv[2], 0.0f));
            float sh = sqrtf(fmaxf(b3, 0.0f)) - sqrtf(fmaxf(tv[3], 0.0f));
            dwh[b] = sw * sw + sh * sh;
            conf[b] = b4;
        }

        int best = (iou[1] > iou[0]) ? 1 : 0;   // argmax ties -> first (box 0)

        #pragma unroll
        for (int b = 0; b < 2; ++b) {
            float resp_obj = (b == best) ? obj : 0.0f;
            acc += 5.0f * resp_obj * (dxy[b] + dwh[b]);          // coord
            float d = conf[b] - iou[b];
            acc += resp_obj * d * d;                              // conf obj
            acc += 0.5f * (1.0f - resp_obj) * conf[b] * conf[b];  // conf noobj
        }
    } else {
        // ---- class waves: obj * sum((pred_cls - gt_cls)^2) ----
        float obj = (tv[4] > 0.5f) ? 1.0f : 0.0f;
        float cls = 0.0f;
        #pragma unroll
        for (int c = 0; c < 20; ++c) {
            float d = pv[10 + c] - tv[5 + c];
            cls += d * d;
        }
        acc = obj * cls;
    }

    // ---- per-wave reduce, then block sum ----
    #pragma unroll
    for (int off = 32; off > 0; off >>= 1)
        acc += __shfl_down(acc, off, 64);
    if (lane == 0) sred[wid] = acc;
    __syncthreads();
    if (t == 0) partial[bid] = sred[0] + sred[1] + sred[2] + sred[3];
}

__global__ __launch_bounds__(1024) void yolo_final_kernel(
    const float* __restrict__ partial, int n4, float* __restrict__ out, float invN)
{
    const float4* p4 = reinterpret_cast<const float4*>(partial);
    float s = 0.0f;
    for (int i = threadIdx.x; i < n4; i += 1024) {
        float4 v = p4[i];
        s += (v.x + v.y) + (v.z + v.w);
    }
    #pragma unroll
    for (int off = 32; off > 0; off >>= 1)
        s += __shfl_down(s, off, 64);

    __shared__ float smem[16];
    int lane = threadIdx.x & 63;
    int wid  = threadIdx.x >> 6;
    if (lane == 0) smem[wid] = s;
    __syncthreads();
    if (threadIdx.x == 0) {
        float r = 0.0f;
        #pragma unroll
        for (int w = 0; w < 16; ++w) r += smem[w];
        out[0] = r * invN;
    }
}

extern "C" void kernel_launch(void* const* d_in, const int* in_sizes, int n_in,
                              void* d_out, int out_size, void* d_ws, size_t ws_size,
                              hipStream_t stream)
{
    const float* pred = (const float*)d_in[0];
    const float* tgt  = (const float*)d_in[1];
    float* out        = (float*)d_out;
    float* partial    = (float*)d_ws;

    int ncells  = in_sizes[0] / CELL_P;   // N*S*S = 802816
    int N       = ncells / 49;
    int nblocks = ncells / CPB;           // 6272, no tail

    yolo_cell_kernel<<<nblocks, TPB, 0, stream>>>(pred, tgt, partial);
    yolo_final_kernel<<<1, 1024, 0, stream>>>(partial, nblocks / 4, out,
                                              1.0f / (float)N);
}